// Round 1
// baseline (638.494 us; speedup 1.0000x reference)
//
#include <hip/hip_runtime.h>

// AdjacencyGenerator: only layer L-1 of the attention loop is live (q,k,v are
// loop-invariant and attn_output/query are overwritten), the MLP is affine
// (composes to one 128x128 matrix A + bias cfull), and relu(alpha*v) ==
// alpha*relu(v) since softmax alpha > 0. So:
//   per node: Q,K,V = x@W{q,k,v}2^T + b ; U = relu(V) ; VM = U@A^T
//   per edge: alpha = softmax_dst(Q[src].K[dst]) (max-shift dropped: exactly
//             equivalent, no overflow since |alpha| <~ 25)
//   logit = LN( alpha*VM[dst] + cfull + LN(x[dst]+alpha*U[dst])*g+b ) . (fg*wv)
//           ... + fb.wv + bvec
// Workspace (fp32): A 16384 | T 32768 | cfull 128 | Q,K,U,VM N*128 each |
//                   eArr E | sArr N  ~= 106 MB.

// ============ tiny parameter-composition kernels ============
// T = W2 @ W1   [256,128], K=512
__global__ void k_T(const float* __restrict__ W2, const float* __restrict__ W1,
                    float* __restrict__ T) {
  const int i = blockIdx.x;   // 256
  const int j = threadIdx.x;  // 128
  float acc = 0.f;
  for (int k = 0; k < 512; ++k) acc += W2[i * 512 + k] * W1[k * 128 + j];
  T[i * 128 + j] = acc;
}

// A = W3 @ T   [128,128], K=256
__global__ void k_A(const float* __restrict__ W3, const float* __restrict__ T,
                    float* __restrict__ A) {
  const int i = blockIdx.x;   // 128
  const int j = threadIdx.x;  // 128
  float acc = 0.f;
  for (int k = 0; k < 256; ++k) acc += W3[i * 256 + k] * T[k * 128 + j];
  A[i * 128 + j] = acc;
}

// cfull = W3 @ (W2 @ b1 + b2) + b3   [128]
__global__ void k_c(const float* __restrict__ W2, const float* __restrict__ b1,
                    const float* __restrict__ b2, const float* __restrict__ W3,
                    const float* __restrict__ b3, float* __restrict__ cfull) {
  __shared__ float t1[256];
  const int t = threadIdx.x;  // 256
  float acc = b2[t];
  for (int c = 0; c < 512; ++c) acc += W2[t * 512 + c] * b1[c];
  t1[t] = acc;
  __syncthreads();
  if (t < 128) {
    float a = b3[t];
    for (int k = 0; k < 256; ++k) a += W3[t * 256 + k] * t1[k];
    cfull[t] = a;
  }
}

// ============ node-level GEMV tiles ============
// Block = 256 threads over a 64-node tile. thread -> (node j = t&63,
// row-chunk rc = t>>6 covering rows [32rc,32rc+32)). x tile staged in LDS
// [64][129] (pad 1 -> conflict-free broadcast-ish reads). Weight reads are
// wave-uniform (rc via readfirstlane) -> scalar loads from L2.
__device__ __forceinline__ void gemv_tile(const float (*__restrict__ xs)[129],
                                          int j, int rbase,
                                          const float* __restrict__ W,
                                          const float* __restrict__ bias,
                                          float* __restrict__ outp, int n,
                                          int N, bool do_relu) {
  float acc[32];
#pragma unroll
  for (int r = 0; r < 32; ++r) acc[r] = bias ? bias[rbase + r] : 0.f;
  for (int cc = 0; cc < 16; ++cc) {
    float xv[8];
#pragma unroll
    for (int w = 0; w < 8; ++w) xv[w] = xs[j][cc * 8 + w];
#pragma unroll
    for (int r = 0; r < 32; ++r) {
#pragma unroll
      for (int w = 0; w < 8; ++w)
        acc[r] += W[(rbase + r) * 128 + cc * 8 + w] * xv[w];
    }
  }
  if (n < N) {
#pragma unroll
    for (int r = 0; r < 32; ++r) {
      float v = acc[r];
      if (do_relu) v = v > 0.f ? v : 0.f;
      outp[(size_t)n * 128 + rbase + r] = v;
    }
  }
}

__device__ __forceinline__ void stage_tile(float (*__restrict__ xs)[129],
                                           const float* __restrict__ src,
                                           int nb, int N) {
  const int t = threadIdx.x;
  for (int i = t; i < 64 * 32; i += 256) {
    const int j = i >> 5, c4 = i & 31;
    const int n = nb + j;
    float4 v = make_float4(0.f, 0.f, 0.f, 0.f);
    if (n < N) v = ((const float4*)src)[(size_t)n * 32 + c4];
    xs[j][c4 * 4 + 0] = v.x;
    xs[j][c4 * 4 + 1] = v.y;
    xs[j][c4 * 4 + 2] = v.z;
    xs[j][c4 * 4 + 3] = v.w;
  }
}

__global__ __launch_bounds__(256) void k_nodeQKV(
    const float* __restrict__ x, const float* __restrict__ Wq,
    const float* __restrict__ bq, const float* __restrict__ Wk,
    const float* __restrict__ bk, const float* __restrict__ Wv,
    const float* __restrict__ bv, float* __restrict__ Q,
    float* __restrict__ Kk, float* __restrict__ U, int N) {
  __shared__ float xs[64][129];
  const int nb = blockIdx.x * 64;
  stage_tile(xs, x, nb, N);
  __syncthreads();
  const int j = threadIdx.x & 63;
  const int rc = __builtin_amdgcn_readfirstlane(threadIdx.x >> 6);
  const int n = nb + j;
  const int rbase = rc * 32;
  gemv_tile(xs, j, rbase, Wq, bq, Q, n, N, false);
  gemv_tile(xs, j, rbase, Wk, bk, Kk, n, N, false);
  gemv_tile(xs, j, rbase, Wv, bv, U, n, N, true);
}

__global__ __launch_bounds__(256) void k_nodeVM(const float* __restrict__ U,
                                                const float* __restrict__ A,
                                                float* __restrict__ VM, int N) {
  __shared__ float xs[64][129];
  const int nb = blockIdx.x * 64;
  stage_tile(xs, U, nb, N);
  __syncthreads();
  const int j = threadIdx.x & 63;
  const int rc = __builtin_amdgcn_readfirstlane(threadIdx.x >> 6);
  const int n = nb + j;
  gemv_tile(xs, j, rc * 32, A, nullptr, VM, n, N, false);
}

// ============ edge pass 1: alpha = Q[src].K[dst]; e=exp(alpha); s[dst]+=e ====
// Half-wave (32 lanes) per edge: coalesced 512B row loads, 5-step butterfly.
__global__ __launch_bounds__(256) void k_edge_alpha(
    const int* __restrict__ ei, const float* __restrict__ Q,
    const float* __restrict__ Kk, float* __restrict__ eArr,
    float* __restrict__ sArr, int E) {
  const int t = threadIdx.x;
  const int l = t & 31;
  const int e = blockIdx.x * 8 + (t >> 5);
  if (e >= E) return;
  const int src = ei[e];
  const int dst = ei[E + e];
  const float4 a = ((const float4*)Q)[(size_t)src * 32 + l];
  const float4 b = ((const float4*)Kk)[(size_t)dst * 32 + l];
  float p = a.x * b.x + a.y * b.y + a.z * b.z + a.w * b.w;
#pragma unroll
  for (int m = 16; m >= 1; m >>= 1) p += __shfl_xor(p, m, 32);
  if (l == 0) {
    const float ex = __expf(p);  // max-shift dropped: exactly equivalent
    eArr[e] = ex;
    atomicAdd(&sArr[dst], ex);
  }
}

// ============ edge pass 2: fused LN + MLP-collapse + LN + logit ============
__global__ __launch_bounds__(256) void k_edge_out(
    const int* __restrict__ ei, const float* __restrict__ x,
    const float* __restrict__ U, const float* __restrict__ VM,
    const float* __restrict__ eArr, const float* __restrict__ sArr,
    const float* __restrict__ cfull, const float* __restrict__ g128,
    const float* __restrict__ b128, const float* __restrict__ fg,
    const float* __restrict__ fb, const float* __restrict__ wv,
    const float* __restrict__ bvec, float* __restrict__ out, int E) {
  const int t = threadIdx.x;
  const int l = t & 31;
  const int e = blockIdx.x * 8 + (t >> 5);
  if (e >= E) return;
  const int dst = ei[E + e];
  const float ta = eArr[e] / (sArr[dst] + 1e-16f);

  const float4 xd = ((const float4*)x)[(size_t)dst * 32 + l];
  const float4 uu = ((const float4*)U)[(size_t)dst * 32 + l];
  const float4 vm = ((const float4*)VM)[(size_t)dst * 32 + l];
  const float4 gg = ((const float4*)g128)[l];
  const float4 bb = ((const float4*)b128)[l];
  const float4 cf = ((const float4*)cfull)[l];
  const float4 fgv = ((const float4*)fg)[l];
  const float4 fbv = ((const float4*)fb)[l];
  const float4 wvv = ((const float4*)wv)[l];

  // y1 = x[dst] + ta*U[dst]; first layernorm stats
  const float y0 = xd.x + ta * uu.x, y1 = xd.y + ta * uu.y,
              y2 = xd.z + ta * uu.z, y3 = xd.w + ta * uu.w;
  float s1 = y0 + y1 + y2 + y3;
  float s2 = y0 * y0 + y1 * y1 + y2 * y2 + y3 * y3;
#pragma unroll
  for (int m = 16; m >= 1; m >>= 1) {
    s1 += __shfl_xor(s1, m, 32);
    s2 += __shfl_xor(s2, m, 32);
  }
  const float mu1 = s1 * (1.f / 128.f);
  const float var1 = s2 * (1.f / 128.f) - mu1 * mu1;
  const float inv1 = rsqrtf(var1 + 1e-5f);

  // z = ta*VM[dst] + cfull + LN(y1)*g + b   (= MLP(attn) + query)
  const float z0 = ta * vm.x + cf.x + (y0 - mu1) * inv1 * gg.x + bb.x;
  const float z1 = ta * vm.y + cf.y + (y1 - mu1) * inv1 * gg.y + bb.y;
  const float z2 = ta * vm.z + cf.z + (y2 - mu1) * inv1 * gg.z + bb.z;
  const float z3 = ta * vm.w + cf.w + (y3 - mu1) * inv1 * gg.w + bb.w;

  const float w0 = fgv.x * wvv.x, w1 = fgv.y * wvv.y, w2 = fgv.z * wvv.z,
              w3 = fgv.w * wvv.w;

  float sz = z0 + z1 + z2 + z3;
  float szz = z0 * z0 + z1 * z1 + z2 * z2 + z3 * z3;
  float szw = z0 * w0 + z1 * w1 + z2 * w2 + z3 * w3;
  float sw = w0 + w1 + w2 + w3;
  float s0 = fbv.x * wvv.x + fbv.y * wvv.y + fbv.z * wvv.z + fbv.w * wvv.w;
#pragma unroll
  for (int m = 16; m >= 1; m >>= 1) {
    sz += __shfl_xor(sz, m, 32);
    szz += __shfl_xor(szz, m, 32);
    szw += __shfl_xor(szw, m, 32);
    sw += __shfl_xor(sw, m, 32);
    s0 += __shfl_xor(s0, m, 32);
  }
  if (l == 0) {
    const float muz = sz * (1.f / 128.f);
    const float varz = szz * (1.f / 128.f) - muz * muz;
    const float invz = rsqrtf(varz + 1e-5f);
    out[e] = invz * (szw - muz * sw) + s0 + bvec[0];
  }
}

extern "C" void kernel_launch(void* const* d_in, const int* in_sizes, int n_in,
                              void* d_out, int out_size, void* d_ws,
                              size_t ws_size, hipStream_t stream) {
  const int* ei = (const int*)d_in[0];
  const float* x = (const float*)d_in[1];
  const float* Wq = (const float*)d_in[2];
  const float* bq = (const float*)d_in[3];
  const float* Wk = (const float*)d_in[4];
  const float* bk = (const float*)d_in[5];
  const float* Wv = (const float*)d_in[6];
  const float* bv = (const float*)d_in[7];
  const float* ln_g = (const float*)d_in[8];
  const float* ln_b = (const float*)d_in[9];
  const float* W1 = (const float*)d_in[10];
  const float* b1 = (const float*)d_in[11];
  const float* W2 = (const float*)d_in[12];
  const float* b2 = (const float*)d_in[13];
  const float* W3 = (const float*)d_in[14];
  const float* b3 = (const float*)d_in[15];
  const float* Wvec = (const float*)d_in[16];
  const float* bvec = (const float*)d_in[17];
  const float* fn_g = (const float*)d_in[18];
  const float* fn_b = (const float*)d_in[19];

  const int E = in_sizes[0] / 2;
  const int N = in_sizes[1] / 128;

  // only the last layer (index 2) of the attention stack is live
  const float* Wq2 = Wq + 2 * 128 * 128;
  const float* bq2 = bq + 2 * 128;
  const float* Wk2 = Wk + 2 * 128 * 128;
  const float* bk2 = bk + 2 * 128;
  const float* Wv2 = Wv + 2 * 128 * 128;
  const float* bv2 = bv + 2 * 128;
  const float* g2 = ln_g + 2 * 128;
  const float* lb2 = ln_b + 2 * 128;

  float* ws = (float*)d_ws;
  float* A = ws;               // 16384
  float* T = A + 16384;        // 32768
  float* cfull = T + 32768;    // 128
  float* Q = cfull + 128;      // N*128
  float* Kk = Q + (size_t)N * 128;
  float* U = Kk + (size_t)N * 128;
  float* VM = U + (size_t)N * 128;
  float* eArr = VM + (size_t)N * 128;  // E
  float* sArr = eArr + E;              // N

  hipMemsetAsync(sArr, 0, (size_t)N * sizeof(float), stream);

  k_T<<<256, 128, 0, stream>>>(W2, W1, T);
  k_A<<<128, 128, 0, stream>>>(W3, T, A);
  k_c<<<1, 256, 0, stream>>>(W2, b1, b2, W3, b3, cfull);

  const int nblk = (N + 63) / 64;
  k_nodeQKV<<<nblk, 256, 0, stream>>>(x, Wq2, bq2, Wk2, bk2, Wv2, bv2, Q, Kk,
                                      U, N);
  k_nodeVM<<<nblk, 256, 0, stream>>>(U, A, VM, N);

  const int eblk = (E + 7) / 8;
  k_edge_alpha<<<eblk, 256, 0, stream>>>(ei, Q, Kk, eArr, sArr, E);
  k_edge_out<<<eblk, 256, 0, stream>>>(ei, x, U, VM, eArr, sArr, cfull, g2,
                                       lb2, fn_g, fn_b, Wvec, bvec,
                                       (float*)d_out, E);
}

// Round 2
// 297.679 us; speedup vs baseline: 2.1449x; 2.1449x over previous
//
#include <hip/hip_runtime.h>

// AdjacencyGenerator — round 2.
// Algebra (validated in round 1): only layer 2 of the attention stack is
// live; MLP is affine -> one matrix A3 = W3@W2@W1 + bias cfull;
// relu(alpha*v) = alpha*relu(v).
// Round-2 structure:
//   k_node (MFMA bf16): Q,K (bf16 out), U=relu(V) (fp32+LDS bf16), VM=U@A3^T.
//   k_nodeS: per-node 23-scalar collapse of LN->affine->LN->dot pipeline.
//   k_edge_alpha: alpha = Q[src].K[dst] (bf16 gather), exp, atomic segment sum.
//   k_edge_out: closed-form logit from (dst scalars, t=alpha) only.

typedef __attribute__((ext_vector_type(8))) short bf16x8;
typedef __attribute__((ext_vector_type(4))) float f32x4;

__device__ __forceinline__ unsigned short f2bf(float f) {  // RNE
  unsigned int u = __float_as_uint(f);
  unsigned int r = (u + 0x7fffu + ((u >> 16) & 1u)) >> 16;
  return (unsigned short)r;
}
__device__ __forceinline__ float blo(unsigned int u) {
  return __uint_as_float(u << 16);
}
__device__ __forceinline__ float bhi(unsigned int u) {
  return __uint_as_float(u & 0xffff0000u);
}

// ============ parameter composition (fp32, tiny) ============
__global__ void k_T(const float* __restrict__ W2, const float* __restrict__ W1,
                    float* __restrict__ T) {
  const int i = blockIdx.x, j = threadIdx.x;
  float acc = 0.f;
  for (int k = 0; k < 512; ++k) acc += W2[i * 512 + k] * W1[k * 128 + j];
  T[i * 128 + j] = acc;
}
__global__ void k_A(const float* __restrict__ W3, const float* __restrict__ T,
                    float* __restrict__ A) {
  const int i = blockIdx.x, j = threadIdx.x;
  float acc = 0.f;
  for (int k = 0; k < 256; ++k) acc += W3[i * 256 + k] * T[k * 128 + j];
  A[i * 128 + j] = acc;
}
__global__ void k_c(const float* __restrict__ W2, const float* __restrict__ b1,
                    const float* __restrict__ b2, const float* __restrict__ W3,
                    const float* __restrict__ b3, float* __restrict__ cfull) {
  __shared__ float t1[256];
  const int t = threadIdx.x;
  float acc = b2[t];
  for (int c = 0; c < 512; ++c) acc += W2[t * 512 + c] * b1[c];
  t1[t] = acc;
  __syncthreads();
  if (t < 128) {
    float a = b3[t];
    for (int k = 0; k < 256; ++k) a += W3[t * 256 + k] * t1[k];
    cfull[t] = a;
  }
}

// convert Wq2,Wk2,Wv2,A3f (each 128x128 fp32 row-major) to bf16
__global__ __launch_bounds__(256) void k_wcvt(
    const float* __restrict__ Wq, const float* __restrict__ Wk,
    const float* __restrict__ Wv, const float* __restrict__ A3f,
    unsigned short* __restrict__ Wqb, unsigned short* __restrict__ Wkb,
    unsigned short* __restrict__ Wvb, unsigned short* __restrict__ A3b) {
  const int idx = blockIdx.x * 256 + threadIdx.x;  // 4*16384 total
  const int m = idx >> 14, i = idx & 16383;
  const float* s = (m == 0) ? Wq : (m == 1) ? Wk : (m == 2) ? Wv : A3f;
  unsigned short* d = (m == 0) ? Wqb : (m == 1) ? Wkb : (m == 2) ? Wvb : A3b;
  d[i] = f2bf(s[i]);
}

// global constants for the closed-form edge evaluation
__global__ void k_consts(const float* __restrict__ cfull,
                         const float* __restrict__ g,
                         const float* __restrict__ lb,
                         const float* __restrict__ fg,
                         const float* __restrict__ fb,
                         const float* __restrict__ wv, float* __restrict__ C) {
  const int l = threadIdx.x;  // 64
  const float2 gv = ((const float2*)g)[l];
  const float2 bv = ((const float2*)lb)[l];
  const float2 cv = ((const float2*)cfull)[l];
  const float2 fgv = ((const float2*)fg)[l];
  const float2 fbv = ((const float2*)fb)[l];
  const float2 wvv = ((const float2*)wv)[l];
  const float P0 = cv.x + bv.x, P1 = cv.y + bv.y;
  const float w0 = fgv.x * wvv.x, w1 = fgv.y * wvv.y;
  float s[9];
  s[0] = P0 + P1;                          // SP
  s[1] = P0 * w0 + P1 * w1;                // SPw
  s[2] = P0 * P0 + P1 * P1;                // SPP
  s[3] = gv.x + gv.y;                      // SG
  s[4] = gv.x * w0 + gv.y * w1;            // SGw
  s[5] = gv.x * gv.x + gv.y * gv.y;        // GG
  s[6] = P0 * gv.x + P1 * gv.y;            // SPG
  s[7] = w0 + w1;                          // Sw
  s[8] = fbv.x * wvv.x + fbv.y * wvv.y;    // s0
#pragma unroll
  for (int m = 32; m >= 1; m >>= 1)
#pragma unroll
    for (int i = 0; i < 9; ++i) s[i] += __shfl_xor(s[i], m, 64);
  if (l == 0)
#pragma unroll
    for (int i = 0; i < 9; ++i) C[i] = s[i];
}

// ============ fused node MFMA kernel: Q,K,U, VM ============
// Block 256 = 4 waves; tile = 64 nodes; wave w owns rows [16w,16w+16).
// MFMA 16x16x32 bf16: A-frag lane l -> X[m=l&15][k=32kb+8*(l>>4)+i];
// B-frag lane l -> W[n=l&15 (+16cb)][same k]; C/D: row=(l>>4)*4+r, col=l&15.
template <int MODE>  // 0: bf16 out  1: relu -> fp32 out + us bf16  2: fp32 out
__device__ __forceinline__ void mat_pass(
    const unsigned short* __restrict__ Wb, const float* __restrict__ bias,
    unsigned short* __restrict__ outB, float* __restrict__ outF,
    unsigned short (*__restrict__ us)[136], const bf16x8* af, int nb, int wv16,
    int ln, int g4, int N) {
#pragma unroll
  for (int cb = 0; cb < 8; ++cb) {
    f32x4 acc = {0.f, 0.f, 0.f, 0.f};
#pragma unroll
    for (int kb = 0; kb < 4; ++kb) {
      const bf16x8 bfr = *(const bf16x8*)(Wb + ((cb * 16 + ln) << 7) +
                                          kb * 32 + g4 * 8);
      acc = __builtin_amdgcn_mfma_f32_16x16x32_bf16(af[kb], bfr, acc, 0, 0, 0);
    }
    const int col = cb * 16 + ln;
    const float bs = (MODE == 2) ? 0.f : bias[col];
#pragma unroll
    for (int r = 0; r < 4; ++r) {
      const int lr = wv16 + g4 * 4 + r;
      const int n = nb + lr;
      float v = acc[r] + bs;
      if (MODE == 0) {
        if (n < N) outB[(size_t)n * 128 + col] = f2bf(v);
      } else if (MODE == 1) {
        v = fmaxf(v, 0.f);
        if (n < N) outF[(size_t)n * 128 + col] = v;
        us[lr][col] = f2bf(v);
      } else {
        if (n < N) outF[(size_t)n * 128 + col] = v;
      }
    }
  }
}

__global__ __launch_bounds__(256) void k_node(
    const float* __restrict__ x, const unsigned short* __restrict__ Wqb,
    const unsigned short* __restrict__ Wkb,
    const unsigned short* __restrict__ Wvb,
    const unsigned short* __restrict__ A3b, const float* __restrict__ bq,
    const float* __restrict__ bk, const float* __restrict__ bv,
    unsigned short* __restrict__ Qb, unsigned short* __restrict__ Kb,
    float* __restrict__ U, float* __restrict__ VM, int N) {
  __shared__ unsigned short xs[64][136];
  __shared__ unsigned short us[64][136];
  const int t = threadIdx.x;
  const int nb = blockIdx.x * 64;
  // stage x -> bf16 LDS
  for (int i = t; i < 64 * 32; i += 256) {
    const int j = i >> 5, c4 = i & 31;
    const int n = nb + j;
    float4 v = make_float4(0.f, 0.f, 0.f, 0.f);
    if (n < N) v = ((const float4*)x)[(size_t)n * 32 + c4];
    unsigned int lo = f2bf(v.x) | ((unsigned int)f2bf(v.y) << 16);
    unsigned int hi = f2bf(v.z) | ((unsigned int)f2bf(v.w) << 16);
    *(uint2*)&xs[j][c4 << 2] = make_uint2(lo, hi);
  }
  __syncthreads();
  const int wv16 = __builtin_amdgcn_readfirstlane(t >> 6) * 16;
  const int l = t & 63;
  const int ln = l & 15, g4 = l >> 4;
  bf16x8 af[4];
#pragma unroll
  for (int kb = 0; kb < 4; ++kb)
    af[kb] = *(const bf16x8*)&xs[wv16 + ln][kb * 32 + g4 * 8];
  mat_pass<0>(Wqb, bq, Qb, nullptr, nullptr, af, nb, wv16, ln, g4, N);
  mat_pass<0>(Wkb, bk, Kb, nullptr, nullptr, af, nb, wv16, ln, g4, N);
  mat_pass<1>(Wvb, bv, nullptr, U, us, af, nb, wv16, ln, g4, N);
  // VM = U @ A3^T  (per-wave rows only -> no barrier needed)
  bf16x8 af2[4];
#pragma unroll
  for (int kb = 0; kb < 4; ++kb)
    af2[kb] = *(const bf16x8*)&us[wv16 + ln][kb * 32 + g4 * 8];
  mat_pass<2>(A3b, nullptr, nullptr, VM, nullptr, af2, nb, wv16, ln, g4, N);
}

// ============ per-node scalar collapse ============
// wave per node; lane l owns elements {2l, 2l+1}; 23 sums via butterfly.
__global__ __launch_bounds__(256) void k_nodeS(
    const float* __restrict__ x, const float* __restrict__ U,
    const float* __restrict__ VM, const float* __restrict__ cfull,
    const float* __restrict__ g, const float* __restrict__ lb,
    const float* __restrict__ fg, const float* __restrict__ wv,
    float* __restrict__ S, int N) {
  const int t = threadIdx.x;
  const int n = blockIdx.x * 4 + (t >> 6);
  if (n >= N) return;
  const int l = t & 63;
  const float2 xv = ((const float2*)x)[(size_t)n * 64 + l];
  const float2 uv = ((const float2*)U)[(size_t)n * 64 + l];
  const float2 vv = ((const float2*)VM)[(size_t)n * 64 + l];
  const float2 gv = ((const float2*)g)[l];
  const float2 bv = ((const float2*)lb)[l];
  const float2 cv = ((const float2*)cfull)[l];
  const float2 fgv = ((const float2*)fg)[l];
  const float2 wvv = ((const float2*)wv)[l];
  const float P0 = cv.x + bv.x, P1 = cv.y + bv.y;
  const float w0 = fgv.x * wvv.x, w1 = fgv.y * wvv.y;
  const float xg0 = xv.x * gv.x, xg1 = xv.y * gv.y;
  const float ug0 = uv.x * gv.x, ug1 = uv.y * gv.y;
  float s[23];
  s[0] = xv.x + xv.y;
  s[1] = uv.x + uv.y;
  s[2] = xv.x * xv.x + xv.y * xv.y;
  s[3] = xv.x * uv.x + xv.y * uv.y;
  s[4] = uv.x * uv.x + uv.y * uv.y;
  s[5] = vv.x + vv.y;
  s[6] = vv.x * w0 + vv.y * w1;
  s[7] = xg0 + xg1;
  s[8] = ug0 + ug1;
  s[9] = xg0 * w0 + xg1 * w1;
  s[10] = ug0 * w0 + ug1 * w1;
  s[11] = P0 * vv.x + P1 * vv.y;
  s[12] = vv.x * vv.x + vv.y * vv.y;
  s[13] = P0 * xg0 + P1 * xg1;
  s[14] = P0 * ug0 + P1 * ug1;
  s[15] = vv.x * xg0 + vv.y * xg1;
  s[16] = vv.x * ug0 + vv.y * ug1;
  s[17] = vv.x * gv.x + vv.y * gv.y;
  s[18] = xg0 * xg0 + xg1 * xg1;
  s[19] = xg0 * ug0 + xg1 * ug1;
  s[20] = ug0 * ug0 + ug1 * ug1;
  s[21] = xg0 * gv.x + xg1 * gv.y;
  s[22] = ug0 * gv.x + ug1 * gv.y;
#pragma unroll
  for (int m = 32; m >= 1; m >>= 1)
#pragma unroll
    for (int i = 0; i < 23; ++i) s[i] += __shfl_xor(s[i], m, 64);
  if (l == 0) {
    float* o = S + (size_t)n * 24;
    o[0] = s[0] * (1.f / 128.f);  // mx
    o[1] = s[1] * (1.f / 128.f);  // mU
#pragma unroll
    for (int i = 2; i < 23; ++i) o[i] = s[i];
    o[23] = 0.f;
  }
}

// ============ edge pass 1: alpha + segment sum ============
__global__ __launch_bounds__(256) void k_edge_alpha(
    const int* __restrict__ ei, const unsigned short* __restrict__ Qb,
    const unsigned short* __restrict__ Kb, float* __restrict__ eArr,
    float* __restrict__ sArr, int E) {
  const int t = threadIdx.x;
  const int l = t & 15;
  const int e = blockIdx.x * 16 + (t >> 4);
  if (e >= E) return;
  const int src = ei[e];
  const int dst = ei[E + e];
  const uint4 q = ((const uint4*)Qb)[(size_t)src * 16 + l];
  const uint4 k = ((const uint4*)Kb)[(size_t)dst * 16 + l];
  float p = blo(q.x) * blo(k.x);
  p = fmaf(bhi(q.x), bhi(k.x), p);
  p = fmaf(blo(q.y), blo(k.y), p);
  p = fmaf(bhi(q.y), bhi(k.y), p);
  p = fmaf(blo(q.z), blo(k.z), p);
  p = fmaf(bhi(q.z), bhi(k.z), p);
  p = fmaf(blo(q.w), blo(k.w), p);
  p = fmaf(bhi(q.w), bhi(k.w), p);
#pragma unroll
  for (int m = 8; m >= 1; m >>= 1) p += __shfl_xor(p, m, 16);
  if (l == 0) {
    const float ex = __expf(p);  // max-shift dropped: exactly equivalent
    eArr[e] = ex;
    atomicAdd(&sArr[dst], ex);
  }
}

// ============ edge pass 2: closed-form logit ============
__global__ __launch_bounds__(256) void k_edge_out(
    const int* __restrict__ ei, const float* __restrict__ eArr,
    const float* __restrict__ sArr, const float* __restrict__ S,
    const float* __restrict__ C, const float* __restrict__ bvec,
    float* __restrict__ out, int E) {
  const int e = blockIdx.x * 256 + threadIdx.x;
  if (e >= E) return;
  const int dst = ei[E + e];
  const float t = eArr[e] / (sArr[dst] + 1e-16f);
  const float4* o = (const float4*)(S + (size_t)dst * 24);
  const float4 q0 = o[0], q1 = o[1], q2 = o[2], q3 = o[3], q4 = o[4],
               q5 = o[5];
  const float mx = q0.x, mU = q0.y, sxx = q0.z, sxu = q0.w;
  const float suu = q1.x, sv = q1.y, svw = q1.z, sxg = q1.w;
  const float sug = q2.x, sxgw = q2.y, sugw = q2.z, spv = q2.w;
  const float svv = q3.x, pxg = q3.y, pug = q3.z, vxg = q3.w;
  const float vug = q4.x, vg = q4.y, xgxg = q4.z, xgug = q4.w;
  const float ugug = q5.x, xgg = q5.y, ugg = q5.z;
  const float SP = C[0], SPw = C[1], SPP = C[2], SG = C[3], SGw = C[4],
              GG = C[5], SPG = C[6], Sw = C[7], s0 = C[8];
  const float mu = mx + t * mU;
  const float qy = (sxx + 2.f * t * sxu + t * t * suu) * (1.f / 128.f);
  const float i1 = rsqrtf(qy - mu * mu + 1e-5f);
  const float sz = SP + t * sv + i1 * (sxg + t * sug - mu * SG);
  const float szw = SPw + t * svw + i1 * (sxgw + t * sugw - mu * SGw);
  const float cross = pxg + t * (pug + vxg) + t * t * vug - mu * (SPG + t * vg);
  const float rr = xgxg + 2.f * t * xgug + t * t * ugug -
                   2.f * mu * (xgg + t * ugg) + mu * mu * GG;
  const float szz =
      SPP + 2.f * t * spv + t * t * svv + 2.f * i1 * cross + i1 * i1 * rr;
  const float muz = sz * (1.f / 128.f);
  const float varz = szz * (1.f / 128.f) - muz * muz;
  const float iz = rsqrtf(varz + 1e-5f);
  out[e] = iz * (szw - muz * Sw) + s0 + bvec[0];
}

extern "C" void kernel_launch(void* const* d_in, const int* in_sizes, int n_in,
                              void* d_out, int out_size, void* d_ws,
                              size_t ws_size, hipStream_t stream) {
  const int* ei = (const int*)d_in[0];
  const float* x = (const float*)d_in[1];
  const float* Wq = (const float*)d_in[2];
  const float* bq = (const float*)d_in[3];
  const float* Wk = (const float*)d_in[4];
  const float* bk = (const float*)d_in[5];
  const float* Wv = (const float*)d_in[6];
  const float* bv = (const float*)d_in[7];
  const float* ln_g = (const float*)d_in[8];
  const float* ln_b = (const float*)d_in[9];
  const float* W1 = (const float*)d_in[10];
  const float* b1 = (const float*)d_in[11];
  const float* W2 = (const float*)d_in[12];
  const float* b2 = (const float*)d_in[13];
  const float* W3 = (const float*)d_in[14];
  const float* b3 = (const float*)d_in[15];
  const float* Wvec = (const float*)d_in[16];
  const float* bvec = (const float*)d_in[17];
  const float* fn_g = (const float*)d_in[18];
  const float* fn_b = (const float*)d_in[19];

  const int E = in_sizes[0] / 2;
  const int N = in_sizes[1] / 128;

  // only layer 2 is live
  const float* Wq2 = Wq + 2 * 128 * 128;
  const float* bq2 = bq + 2 * 128;
  const float* Wk2 = Wk + 2 * 128 * 128;
  const float* bk2 = bk + 2 * 128;
  const float* Wv2 = Wv + 2 * 128 * 128;
  const float* bv2 = bv + 2 * 128;
  const float* g2 = ln_g + 2 * 128;
  const float* lb2 = ln_b + 2 * 128;

  float* ws = (float*)d_ws;
  float* T = ws;                  // 32768
  float* A3f = T + 32768;         // 16384
  float* cfull = A3f + 16384;     // 128
  float* consts = cfull + 128;    // 16
  unsigned short* Wqb = (unsigned short*)(consts + 16);  // 16384 us each
  unsigned short* Wkb = Wqb + 16384;
  unsigned short* Wvb = Wkb + 16384;
  unsigned short* A3b = Wvb + 16384;
  float* fbase = consts + 16 + 32768;      // after 4*8192 floats of bf16 mats
  unsigned short* Qb = (unsigned short*)fbase;        // N*128 bf16
  unsigned short* Kb = Qb + (size_t)N * 128;
  float* U = fbase + (size_t)N * 128;      // N*128 f32 (after Qb+Kb region)
  float* VM = U + (size_t)N * 128;
  float* S = VM + (size_t)N * 128;         // N*24
  float* eArr = S + (size_t)N * 24;        // E
  float* sArr = eArr + E;                  // N

  hipMemsetAsync(sArr, 0, (size_t)N * sizeof(float), stream);

  k_T<<<256, 128, 0, stream>>>(W2, W1, T);
  k_A<<<128, 128, 0, stream>>>(W3, T, A3f);
  k_c<<<1, 256, 0, stream>>>(W2, b1, b2, W3, b3, cfull);
  k_wcvt<<<256, 256, 0, stream>>>(Wq2, Wk2, Wv2, A3f, Wqb, Wkb, Wvb, A3b);
  k_consts<<<1, 64, 0, stream>>>(cfull, g2, lb2, fn_g, fn_b, Wvec, consts);

  const int nblk = (N + 63) / 64;
  k_node<<<nblk, 256, 0, stream>>>(x, Wqb, Wkb, Wvb, A3b, bq2, bk2, bv2, Qb,
                                   Kb, U, VM, N);
  const int sblk = (N + 3) / 4;
  k_nodeS<<<sblk, 256, 0, stream>>>(x, U, VM, cfull, g2, lb2, fn_g, Wvec, S,
                                    N);
  const int ablk = (E + 15) / 16;
  k_edge_alpha<<<ablk, 256, 0, stream>>>(ei, Qb, Kb, eArr, sArr, E);
  const int oblk = (E + 255) / 256;
  k_edge_out<<<oblk, 256, 0, stream>>>(ei, eArr, sArr, S, consts, bvec,
                                       (float*)d_out, E);
}

// Round 5
// 220.014 us; speedup vs baseline: 2.9021x; 1.3530x over previous
//
#include <hip/hip_runtime.h>

// AdjacencyGenerator — round 5.
// Algebra: only layer 2 live; MLP affine -> A3 = W3@W2@W1 (+cfull);
// relu(alpha*v) = alpha*relu(v); both layernorms + final dot collapse to a
// closed form in the scalar t = alpha given 23 per-node sums S[dst].
// Round-5 fix: round 3/4 computed the 23 sums from bf16-rounded x/U/VM
// (absmax 0.0698 > 0.04875). Restore round-2 fp32 stats numerics inside the
// fused kernel: x staged fp32 in LDS; U and VM kept as fp32 MFMA accumulators
// in registers; only MFMA inputs are bf16 (as validated in round 2, 0.0098).

typedef __attribute__((ext_vector_type(8))) short bf16x8;
typedef __attribute__((ext_vector_type(4))) float f32x4;

__device__ __forceinline__ unsigned short f2bf(float f) {  // RNE
  unsigned int u = __float_as_uint(f);
  unsigned int r = (u + 0x7fffu + ((u >> 16) & 1u)) >> 16;
  return (unsigned short)r;
}
__device__ __forceinline__ float blo(unsigned int u) {
  return __uint_as_float(u << 16);
}
__device__ __forceinline__ float bhi(unsigned int u) {
  return __uint_as_float(u & 0xffff0000u);
}

// ==== setup kernel 1: T = W2@W1 | Wq/Wk/Wv -> bf16 (384 blks) | zero sArr ===
__global__ __launch_bounds__(128) void k_TW(
    const float* __restrict__ W2, const float* __restrict__ W1,
    const float* __restrict__ Wq, const float* __restrict__ Wk,
    const float* __restrict__ Wv, float* __restrict__ T,
    unsigned short* __restrict__ Wqb, unsigned short* __restrict__ Wkb,
    unsigned short* __restrict__ Wvb, float* __restrict__ sArr, int N) {
  const int b = blockIdx.x, t = threadIdx.x;
  if (b < 256) {
    float acc = 0.f;
    for (int k = 0; k < 512; ++k) acc += W2[b * 512 + k] * W1[k * 128 + t];
    T[b * 128 + t] = acc;
  } else if (b < 640) {  // 384 blocks * 128 threads = 3 * 16384 elements
    const int idx = (b - 256) * 128 + t;
    const int m = idx >> 14, i = idx & 16383;
    const float* s = (m == 0) ? Wq : (m == 1) ? Wk : Wv;
    unsigned short* d = (m == 0) ? Wqb : (m == 1) ? Wkb : Wvb;
    d[i] = f2bf(s[i]);
  } else {
    const int i = (b - 640) * 128 + t;
    if (i < N) sArr[i] = 0.f;
  }
}

// ============ setup kernel 2: A3b = bf16(W3@T) | cfull | consts ============
__global__ __launch_bounds__(256) void k_Ac(
    const float* __restrict__ W3, const float* __restrict__ T,
    const float* __restrict__ W2, const float* __restrict__ b1,
    const float* __restrict__ b2, const float* __restrict__ b3,
    const float* __restrict__ g, const float* __restrict__ lb,
    const float* __restrict__ fg, const float* __restrict__ fb,
    const float* __restrict__ wv, unsigned short* __restrict__ A3b,
    float* __restrict__ cfull, float* __restrict__ C) {
  __shared__ float t1[256];
  __shared__ float cf[128];
  const int b = blockIdx.x, t = threadIdx.x;
  if (b < 64) {  // two rows of A3 per block
    const int i = 2 * b + (t >> 7), j = t & 127;
    float acc = 0.f;
    for (int k = 0; k < 256; ++k) acc += W3[i * 256 + k] * T[k * 128 + j];
    A3b[i * 128 + j] = f2bf(acc);
    return;
  }
  // b == 64: cfull = W3@(W2@b1+b2)+b3, then the 9 global consts
  float acc = b2[t];
  for (int c = 0; c < 512; ++c) acc += W2[t * 512 + c] * b1[c];
  t1[t] = acc;
  __syncthreads();
  if (t < 128) {
    float a = b3[t];
    for (int k = 0; k < 256; ++k) a += W3[t * 256 + k] * t1[k];
    cfull[t] = a;
    cf[t] = a;
  }
  __syncthreads();
  if (t < 64) {
    const int l = t;
    const float2 gv = ((const float2*)g)[l];
    const float2 bv = ((const float2*)lb)[l];
    const float2 fgv = ((const float2*)fg)[l];
    const float2 fbv = ((const float2*)fb)[l];
    const float2 wvv = ((const float2*)wv)[l];
    const float P0 = cf[2 * l] + bv.x, P1 = cf[2 * l + 1] + bv.y;
    const float w0 = fgv.x * wvv.x, w1 = fgv.y * wvv.y;
    float s[9];
    s[0] = P0 + P1;
    s[1] = P0 * w0 + P1 * w1;
    s[2] = P0 * P0 + P1 * P1;
    s[3] = gv.x + gv.y;
    s[4] = gv.x * w0 + gv.y * w1;
    s[5] = gv.x * gv.x + gv.y * gv.y;
    s[6] = P0 * gv.x + P1 * gv.y;
    s[7] = w0 + w1;
    s[8] = fbv.x * wvv.x + fbv.y * wvv.y;
#pragma unroll
    for (int m = 32; m >= 1; m >>= 1)
#pragma unroll
      for (int i = 0; i < 9; ++i) s[i] += __shfl_xor(s[i], m, 64);
    if (l == 0)
#pragma unroll
      for (int i = 0; i < 9; ++i) C[i] = s[i];
  }
}

// ============ fused node kernel: Q,K tables + fp32 23-scalar collapse =======
// Block 256 = 4 waves over a 64-node tile; wave w owns rows [16w,16w+16).
// MFMA 16x16x32 bf16: A-frag lane l -> X[m=l&15][k=32kb+8*(l>>4)+i];
// B-frag lane l -> W[n][same k]; C/D: row=(l>>4)*4+r, col=l&15 (+16cb).
__device__ __forceinline__ void qk_pass(const unsigned short* __restrict__ Wb,
                                        const float* __restrict__ bias,
                                        unsigned short* __restrict__ outB,
                                        const bf16x8* af, int nb, int wv16,
                                        int ln, int g4, int N) {
#pragma unroll
  for (int cb = 0; cb < 8; ++cb) {
    f32x4 acc = {0.f, 0.f, 0.f, 0.f};
#pragma unroll
    for (int kb = 0; kb < 4; ++kb) {
      const bf16x8 bfr =
          *(const bf16x8*)(Wb + ((cb * 16 + ln) << 7) + kb * 32 + g4 * 8);
      acc = __builtin_amdgcn_mfma_f32_16x16x32_bf16(af[kb], bfr, acc, 0, 0, 0);
    }
    const int col = cb * 16 + ln;
    const float bs = bias[col];
#pragma unroll
    for (int r = 0; r < 4; ++r) {
      const int lr = wv16 + g4 * 4 + r;
      if (nb + lr < N) outB[(size_t)(nb + lr) * 128 + col] = f2bf(acc[r] + bs);
    }
  }
}

__global__ __launch_bounds__(256) void k_node(
    const float* __restrict__ x, const unsigned short* __restrict__ Wqb,
    const unsigned short* __restrict__ Wkb,
    const unsigned short* __restrict__ Wvb,
    const unsigned short* __restrict__ A3b, const float* __restrict__ bq,
    const float* __restrict__ bk, const float* __restrict__ bv,
    const float* __restrict__ cfull, const float* __restrict__ g,
    const float* __restrict__ lb, const float* __restrict__ fg,
    const float* __restrict__ wvp, unsigned short* __restrict__ Qb,
    unsigned short* __restrict__ Kb, float* __restrict__ S, int N) {
  __shared__ float xf[64][132];            // fp32 x tile (2-way banks: free)
  __shared__ unsigned short uls[64][136];  // bf16 U (VM MFMA input only)
  __shared__ float cg[128], cw[128], cP[128];
  const int t = threadIdx.x;
  const int nb = blockIdx.x * 64;
  if (t < 128) {
    cg[t] = g[t];
    cw[t] = fg[t] * wvp[t];
    cP[t] = cfull[t] + lb[t];
  }
  // stage x -> fp32 LDS
  for (int i = t; i < 64 * 32; i += 256) {
    const int j = i >> 5, c4 = i & 31;
    const int n = nb + j;
    float4 v = make_float4(0.f, 0.f, 0.f, 0.f);
    if (n < N) v = ((const float4*)x)[(size_t)n * 32 + c4];
    *(float4*)&xf[j][c4 * 4] = v;
  }
  __syncthreads();
  const int wv16 = __builtin_amdgcn_readfirstlane(t >> 6) * 16;
  const int l = t & 63;
  const int ln = l & 15, g4 = l >> 4;

  // A-frags: convert fp32 LDS -> bf16 on the fly
  bf16x8 af[4];
#pragma unroll
  for (int kb = 0; kb < 4; ++kb) {
    const float* p = &xf[wv16 + ln][kb * 32 + g4 * 8];
    const float4 a0 = *(const float4*)p;
    const float4 a1 = *(const float4*)(p + 4);
    bf16x8 r;
    r[0] = (short)f2bf(a0.x); r[1] = (short)f2bf(a0.y);
    r[2] = (short)f2bf(a0.z); r[3] = (short)f2bf(a0.w);
    r[4] = (short)f2bf(a1.x); r[5] = (short)f2bf(a1.y);
    r[6] = (short)f2bf(a1.z); r[7] = (short)f2bf(a1.w);
    af[kb] = r;
  }

  qk_pass(Wqb, bq, Qb, af, nb, wv16, ln, g4, N);
  qk_pass(Wkb, bk, Kb, af, nb, wv16, ln, g4, N);

  // V pass: uf fp32 regs (exact) + bf16 copy to LDS for the VM MFMA
  float uf[8][4];
#pragma unroll
  for (int cb = 0; cb < 8; ++cb) {
    f32x4 acc = {0.f, 0.f, 0.f, 0.f};
#pragma unroll
    for (int kb = 0; kb < 4; ++kb) {
      const bf16x8 bfr =
          *(const bf16x8*)(Wvb + ((cb * 16 + ln) << 7) + kb * 32 + g4 * 8);
      acc = __builtin_amdgcn_mfma_f32_16x16x32_bf16(af[kb], bfr, acc, 0, 0, 0);
    }
    const int col = cb * 16 + ln;
    const float bs = bv[col];
#pragma unroll
    for (int r = 0; r < 4; ++r) {
      const float v = fmaxf(acc[r] + bs, 0.f);
      uf[cb][r] = v;
      uls[wv16 + g4 * 4 + r][col] = f2bf(v);
    }
  }

  // VM pass (same-wave rows only -> no barrier): vmf fp32 regs (exact)
  bf16x8 af2[4];
#pragma unroll
  for (int kb = 0; kb < 4; ++kb)
    af2[kb] = *(const bf16x8*)&uls[wv16 + ln][kb * 32 + g4 * 8];
  float vmf[8][4];
#pragma unroll
  for (int cb = 0; cb < 8; ++cb) {
    f32x4 acc = {0.f, 0.f, 0.f, 0.f};
#pragma unroll
    for (int kb = 0; kb < 4; ++kb) {
      const bf16x8 bfr =
          *(const bf16x8*)(A3b + ((cb * 16 + ln) << 7) + kb * 32 + g4 * 8);
      acc = __builtin_amdgcn_mfma_f32_16x16x32_bf16(af2[kb], bfr, acc, 0, 0, 0);
    }
#pragma unroll
    for (int r = 0; r < 4; ++r) vmf[cb][r] = acc[r];
  }

  // hoist fp32 consts at this lane's 8 columns
  float gc[8], wc[8], Pc[8];
#pragma unroll
  for (int cb = 0; cb < 8; ++cb) {
    const int col = cb * 16 + ln;
    gc[cb] = cg[col];
    wc[cb] = cw[col];
    Pc[cb] = cP[col];
  }

  // ---- 23-scalar collapse, all fp32 (round-2 numerics) ----
  // row = wv16 + g4*4 + r; its 128 cols live on the 16 lanes of this g4
  // group (ln=0..15) x 8 cb chunks. Reduce over masks 1,2,4,8.
#pragma unroll
  for (int r = 0; r < 4; ++r) {
    const int row = wv16 + g4 * 4 + r;
    float s[23];
#pragma unroll
    for (int i = 0; i < 23; ++i) s[i] = 0.f;
#pragma unroll
    for (int cb = 0; cb < 8; ++cb) {
      const float xv = xf[row][cb * 16 + ln];
      const float u = uf[cb][r];
      const float v = vmf[cb][r];
      const float gg = gc[cb], ww = wc[cb], PP = Pc[cb];
      const float xg = xv * gg, ug = u * gg;
      s[0] += xv;
      s[1] += u;
      s[2] += xv * xv;
      s[3] += xv * u;
      s[4] += u * u;
      s[5] += v;
      s[6] += v * ww;
      s[7] += xg;
      s[8] += ug;
      s[9] += xg * ww;
      s[10] += ug * ww;
      s[11] += PP * v;
      s[12] += v * v;
      s[13] += PP * xg;
      s[14] += PP * ug;
      s[15] += v * xg;
      s[16] += v * ug;
      s[17] += v * gg;
      s[18] += xg * xg;
      s[19] += xg * ug;
      s[20] += ug * ug;
      s[21] += xg * gg;
      s[22] += ug * gg;
    }
#pragma unroll
    for (int m = 1; m <= 8; m <<= 1)
#pragma unroll
      for (int i = 0; i < 23; ++i) s[i] += __shfl_xor(s[i], m, 64);
    const int n2 = nb + row;
    if (ln == 0 && n2 < N) {
      float* o = S + (size_t)n2 * 24;
      o[0] = s[0] * (1.f / 128.f);
      o[1] = s[1] * (1.f / 128.f);
#pragma unroll
      for (int i = 2; i < 23; ++i) o[i] = s[i];
      o[23] = 0.f;
    }
  }
}

// ============ edge pass 1: alpha + segment sum ============
__global__ __launch_bounds__(256) void k_edge_alpha(
    const int* __restrict__ ei, const unsigned short* __restrict__ Qb,
    const unsigned short* __restrict__ Kb, float* __restrict__ eArr,
    float* __restrict__ sArr, int E) {
  const int t = threadIdx.x;
  const int l = t & 15;
  const int e = blockIdx.x * 16 + (t >> 4);
  if (e >= E) return;
  const int src = ei[e];
  const int dst = ei[E + e];
  const uint4 qv = ((const uint4*)Qb)[(size_t)src * 16 + l];
  const uint4 kv = ((const uint4*)Kb)[(size_t)dst * 16 + l];
  float p = blo(qv.x) * blo(kv.x);
  p = fmaf(bhi(qv.x), bhi(kv.x), p);
  p = fmaf(blo(qv.y), blo(kv.y), p);
  p = fmaf(bhi(qv.y), bhi(kv.y), p);
  p = fmaf(blo(qv.z), blo(kv.z), p);
  p = fmaf(bhi(qv.z), bhi(kv.z), p);
  p = fmaf(blo(qv.w), blo(kv.w), p);
  p = fmaf(bhi(qv.w), bhi(kv.w), p);
#pragma unroll
  for (int m = 8; m >= 1; m >>= 1) p += __shfl_xor(p, m, 16);
  if (l == 0) {
    const float ex = __expf(p);  // max-shift dropped: exactly equivalent
    eArr[e] = ex;
    atomicAdd(&sArr[dst], ex);
  }
}

// ============ edge pass 2: closed-form logit ============
__global__ __launch_bounds__(256) void k_edge_out(
    const int* __restrict__ ei, const float* __restrict__ eArr,
    const float* __restrict__ sArr, const float* __restrict__ S,
    const float* __restrict__ C, const float* __restrict__ bvec,
    float* __restrict__ out, int E) {
  const int e = blockIdx.x * 256 + threadIdx.x;
  if (e >= E) return;
  const int dst = ei[E + e];
  const float t = eArr[e] / (sArr[dst] + 1e-16f);
  const float4* o = (const float4*)(S + (size_t)dst * 24);
  const float4 q0 = o[0], q1 = o[1], q2 = o[2], q3 = o[3], q4 = o[4],
               q5 = o[5];
  const float mx = q0.x, mU = q0.y, sxx = q0.z, sxu = q0.w;
  const float suu = q1.x, sv = q1.y, svw = q1.z, sxg = q1.w;
  const float sug = q2.x, sxgw = q2.y, sugw = q2.z, spv = q2.w;
  const float svv = q3.x, pxg = q3.y, pug = q3.z, vxg = q3.w;
  const float vug = q4.x, vg = q4.y, xgxg = q4.z, xgug = q4.w;
  const float ugug = q5.x, xgg = q5.y, ugg = q5.z;
  const float SP = C[0], SPw = C[1], SPP = C[2], SG = C[3], SGw = C[4],
              GG = C[5], SPG = C[6], Sw = C[7], s0 = C[8];
  const float mu = mx + t * mU;
  const float qy = (sxx + 2.f * t * sxu + t * t * suu) * (1.f / 128.f);
  const float i1 = rsqrtf(qy - mu * mu + 1e-5f);
  const float sz = SP + t * sv + i1 * (sxg + t * sug - mu * SG);
  const float szw = SPw + t * svw + i1 * (sxgw + t * sugw - mu * SGw);
  const float cross = pxg + t * (pug + vxg) + t * t * vug - mu * (SPG + t * vg);
  const float rr = xgxg + 2.f * t * xgug + t * t * ugug -
                   2.f * mu * (xgg + t * ugg) + mu * mu * GG;
  const float szz =
      SPP + 2.f * t * spv + t * t * svv + 2.f * i1 * cross + i1 * i1 * rr;
  const float muz = sz * (1.f / 128.f);
  const float varz = szz * (1.f / 128.f) - muz * muz;
  const float iz = rsqrtf(varz + 1e-5f);
  out[e] = iz * (szw - muz * Sw) + s0 + bvec[0];
}

extern "C" void kernel_launch(void* const* d_in, const int* in_sizes, int n_in,
                              void* d_out, int out_size, void* d_ws,
                              size_t ws_size, hipStream_t stream) {
  const int* ei = (const int*)d_in[0];
  const float* x = (const float*)d_in[1];
  const float* Wq = (const float*)d_in[2];
  const float* bq = (const float*)d_in[3];
  const float* Wk = (const float*)d_in[4];
  const float* bk = (const float*)d_in[5];
  const float* Wv = (const float*)d_in[6];
  const float* bv = (const float*)d_in[7];
  const float* ln_g = (const float*)d_in[8];
  const float* ln_b = (const float*)d_in[9];
  const float* W1 = (const float*)d_in[10];
  const float* b1 = (const float*)d_in[11];
  const float* W2 = (const float*)d_in[12];
  const float* b2 = (const float*)d_in[13];
  const float* W3 = (const float*)d_in[14];
  const float* b3 = (const float*)d_in[15];
  const float* Wvec = (const float*)d_in[16];
  const float* bvec = (const float*)d_in[17];
  const float* fn_g = (const float*)d_in[18];
  const float* fn_b = (const float*)d_in[19];

  const int E = in_sizes[0] / 2;
  const int N = in_sizes[1] / 128;

  // only layer 2 is live
  const float* Wq2 = Wq + 2 * 128 * 128;
  const float* bq2 = bq + 2 * 128;
  const float* Wk2 = Wk + 2 * 128 * 128;
  const float* bk2 = bk + 2 * 128;
  const float* Wv2 = Wv + 2 * 128 * 128;
  const float* bv2 = bv + 2 * 128;
  const float* g2 = ln_g + 2 * 128;
  const float* lb2 = ln_b + 2 * 128;

  float* ws = (float*)d_ws;
  float* T = ws;                 // 32768
  float* cfull = T + 32768;      // 128
  float* consts = cfull + 128;   // 16
  unsigned short* Wqb = (unsigned short*)(consts + 16);  // 16384 us each
  unsigned short* Wkb = Wqb + 16384;
  unsigned short* Wvb = Wkb + 16384;
  unsigned short* A3b = Wvb + 16384;
  float* fbase = consts + 16 + 32768;  // after 4*16384 bf16 = 32768 floats
  unsigned short* Qb = (unsigned short*)fbase;  // N*128 bf16
  unsigned short* Kb = Qb + (size_t)N * 128;
  float* S = fbase + (size_t)N * 128;  // N*24 (after Qb+Kb)
  float* eArr = S + (size_t)N * 24;    // E
  float* sArr = eArr + E;              // N

  const int zblk = (N + 127) / 128;
  k_TW<<<640 + zblk, 128, 0, stream>>>(W2, W1, Wq2, Wk2, Wv2, T, Wqb, Wkb,
                                       Wvb, sArr, N);
  k_Ac<<<65, 256, 0, stream>>>(W3, T, W2, b1, b2, b3, g2, lb2, fn_g, fn_b,
                               Wvec, A3b, cfull, consts);

  const int nblk = (N + 63) / 64;
  k_node<<<nblk, 256, 0, stream>>>(x, Wqb, Wkb, Wvb, A3b, bq2, bk2, bv2,
                                   cfull, g2, lb2, fn_g, Wvec, Qb, Kb, S, N);
  const int ablk = (E + 15) / 16;
  k_edge_alpha<<<ablk, 256, 0, stream>>>(ei, Qb, Kb, eArr, sArr, E);
  const int oblk = (E + 255) / 256;
  k_edge_out<<<oblk, 256, 0, stream>>>(ei, eArr, sArr, S, consts, bvec,
                                       (float*)d_out, E);
}